// Round 1
// baseline (309.667 us; speedup 1.0000x reference)
//
#include <hip/hip_runtime.h>
#include <stdint.h>

// Problem constants (from reference): B=8, T=4096, D=1024, H=32.
#define D_DIM 1024
#define T_DIM 4096
#define B_DIM 8
#define M_REAL (B_DIM * (T_DIM + 1))   // 32776 output rows
#define M_PAD  32896                    // 257 * 128 (GEMM tile padding)

typedef short short8 __attribute__((ext_vector_type(8)));   // 8 bf16 (4 VGPRs)
typedef float floatx4 __attribute__((ext_vector_type(4)));  // 4 fp32 acc

typedef const __attribute__((address_space(1))) void* gptr_t;
typedef __attribute__((address_space(3))) void* lptr_t;

__device__ __forceinline__ ushort f2bf(float f) {
  union { float f; uint32_t u; } v; v.f = f;
  uint32_t r = v.u + 0x7FFF + ((v.u >> 16) & 1);  // RNE
  return (ushort)(r >> 16);
}

// ---------------------------------------------------------------------------
// gemm_bt: C[m,n] = sum_k A[m,k] * B[n,k]  (+ bias[n]); A,B bf16 row-major
// (K contiguous), 128x128 tile, BK=64, 4 waves (2x2 of 64x64), 16x16x32 MFMA.
// m97 structure: global_load_lds width-16 staging, 2 barriers per K-step.
// WRITE_BF16=1 -> Cb (bf16, no bias/guard); 0 -> Cf (fp32, +bias, m<m_limit).
// ---------------------------------------------------------------------------
template<int WRITE_BF16>
__global__ __launch_bounds__(256) void gemm_bt_kernel(
    const ushort* __restrict__ A, const ushort* __restrict__ Bm,
    float* __restrict__ Cf, ushort* __restrict__ Cb,
    const float* __restrict__ bias, int K, int N, int m_limit)
{
  __shared__ ushort As[128][64];   // 16 KB
  __shared__ ushort Bs[128][64];   // 16 KB
  const int tid  = threadIdx.x;
  const int wave = tid >> 6;
  const int lane = tid & 63;
  const int wm = wave >> 1, wn = wave & 1;
  const int m0 = blockIdx.y * 128, n0 = blockIdx.x * 128;
  const int l15 = lane & 15, lhi = lane >> 4;

  floatx4 acc[4][4] = {};

  // Staging map: chunk = q*256 + tid; row = chunk>>3; k8 = (chunk&7)*8.
  // LDS dest is wave-uniform base + lane*16 (HW rule), so base = (q*256+wave*64)*16.
  const int srow = tid >> 3;
  const int sk8  = (tid & 7) * 8;
  const ushort* Ab = A  + (size_t)(m0 + srow) * K + sk8;
  const ushort* Bb = Bm + (size_t)(n0 + srow) * K + sk8;

  for (int k0 = 0; k0 < K; k0 += 64) {
#pragma unroll
    for (int q = 0; q < 4; ++q)
      __builtin_amdgcn_global_load_lds((gptr_t)(Ab + k0 + (size_t)q * 32 * K),
          (lptr_t)((char*)&As[0][0] + (q * 256 + wave * 64) * 16), 16, 0, 0);
#pragma unroll
    for (int q = 0; q < 4; ++q)
      __builtin_amdgcn_global_load_lds((gptr_t)(Bb + k0 + (size_t)q * 32 * K),
          (lptr_t)((char*)&Bs[0][0] + (q * 256 + wave * 64) * 16), 16, 0, 0);
    __syncthreads();

#pragma unroll
    for (int kk = 0; kk < 2; ++kk) {
      short8 af[4], bfr[4];
#pragma unroll
      for (int i = 0; i < 4; ++i) {
        af[i]  = *(const short8*)(&As[wm * 64 + i * 16 + l15][kk * 32 + lhi * 8]);
        bfr[i] = *(const short8*)(&Bs[wn * 64 + i * 16 + l15][kk * 32 + lhi * 8]);
      }
#pragma unroll
      for (int mi = 0; mi < 4; ++mi)
#pragma unroll
        for (int ni = 0; ni < 4; ++ni)
          acc[mi][ni] = __builtin_amdgcn_mfma_f32_16x16x32_bf16(
              af[mi], bfr[ni], acc[mi][ni], 0, 0, 0);
    }
    __syncthreads();
  }

  // Epilogue. C/D layout: col = lane&15, row = (lane>>4)*4 + j (m89-verified).
#pragma unroll
  for (int mi = 0; mi < 4; ++mi)
#pragma unroll
    for (int ni = 0; ni < 4; ++ni) {
      const int gn = n0 + wn * 64 + ni * 16 + l15;
      float bia = 0.0f;
      if (!WRITE_BF16) bia = bias[gn];
#pragma unroll
      for (int j = 0; j < 4; ++j) {
        const int gm = m0 + wm * 64 + mi * 16 + lhi * 4 + j;
        if (WRITE_BF16) {
          Cb[(size_t)gm * N + gn] = f2bf(acc[mi][ni][j]);
        } else {
          if (gm < m_limit) Cf[(size_t)gm * N + gn] = acc[mi][ni][j] + bia;
        }
      }
    }
}

// ---------------------------------------------------------------------------
// Depthwise temporal conv -> s_bf16 [M_PAD][1024].
// s[b,t,:] = sum_{i=0}^{31} w[i] * x[b, t-32+i, :]   (x[neg] = 0), t in [0,4096].
// Stable descending recurrence: s[t-1] = r*s[t] + w0*x[t-33] - (w31*r)*x[t-1].
// Block = (t_chunk of 128, b); 256 threads each own one float4 column.
// ---------------------------------------------------------------------------
__global__ __launch_bounds__(256) void conv_kernel(
    const float* __restrict__ x, const float* __restrict__ dw,
    ushort* __restrict__ S)
{
  const int b  = blockIdx.y;
  const int d4 = threadIdx.x;               // 0..255 (float4 columns)
  const int t0 = blockIdx.x * 128;
  const int t_hi = min(t0 + 127, T_DIM);    // T_DIM = last valid t (4096)

  float w[32];
#pragma unroll
  for (int i = 0; i < 32; ++i) w[i] = dw[i];
  const float r    = w[1] / w[0];
  const float w0   = w[0];
  const float cr32 = w[31] * r;             // C * r^32

  const float4* xb = (const float4*)(x + (size_t)b * T_DIM * D_DIM) + d4;

  float sx = 0.f, sy = 0.f, sz = 0.f, swv = 0.f;
#pragma unroll
  for (int i = 0; i < 32; ++i) {
    const int idx = t_hi - 32 + i;
    if (idx >= 0) {
      float4 v = xb[(size_t)idx * 256];
      sx += w[i] * v.x; sy += w[i] * v.y; sz += w[i] * v.z; swv += w[i] * v.w;
    }
  }
  {
    ushort4 o = make_ushort4(f2bf(sx), f2bf(sy), f2bf(sz), f2bf(swv));
    *(ushort4*)(S + (size_t)(b * (T_DIM + 1) + t_hi) * D_DIM + d4 * 4) = o;
  }
  for (int t = t_hi; t > t0; --t) {
    float ax = 0.f, ay = 0.f, az = 0.f, aw = 0.f;
    const int ia = t - 33;
    if (ia >= 0) {
      float4 v = xb[(size_t)ia * 256];
      ax = v.x; ay = v.y; az = v.z; aw = v.w;
    }
    const float4 vc = xb[(size_t)(t - 1) * 256];
    sx  = r * sx  + w0 * ax - cr32 * vc.x;
    sy  = r * sy  + w0 * ay - cr32 * vc.y;
    sz  = r * sz  + w0 * az - cr32 * vc.z;
    swv = r * swv + w0 * aw - cr32 * vc.w;
    ushort4 o = make_ushort4(f2bf(sx), f2bf(sy), f2bf(sz), f2bf(swv));
    *(ushort4*)(S + (size_t)(b * (T_DIM + 1) + (t - 1)) * D_DIM + d4 * 4) = o;
  }
}

// Zero the GEMM padding rows of S (rows M_REAL..M_PAD-1).
__global__ void zero_pad_kernel(ushort* __restrict__ S) {
  const int row = M_REAL + blockIdx.x;
  *(ushort4*)(S + (size_t)row * D_DIM + threadIdx.x * 4) = make_ushort4(0, 0, 0, 0);
}

// Wo fp32 -> bf16 straight copy.
__global__ void convert_wo_kernel(const float* __restrict__ Wo, ushort* __restrict__ WoB) {
  const int i = blockIdx.x * 256 + threadIdx.x;      // float4 index
  const float4 v = ((const float4*)Wo)[i];
  ushort4 o = make_ushort4(f2bf(v.x), f2bf(v.y), f2bf(v.z), f2bf(v.w));
  *(ushort4*)(WoB + (size_t)i * 4) = o;
}

// Wv fp32 -> WvT bf16 (transpose via LDS 32x32 tile).
__global__ void transpose_wv_kernel(const float* __restrict__ Wv, ushort* __restrict__ WvT) {
  __shared__ float tile[32][33];
  const int tx = threadIdx.x;   // 0..31
  const int ty = threadIdx.y;   // 0..7
  const int c0 = blockIdx.x * 32;
  const int r0 = blockIdx.y * 32;
#pragma unroll
  for (int j = 0; j < 4; ++j)
    tile[ty + j * 8][tx] = Wv[(size_t)(r0 + ty + j * 8) * D_DIM + c0 + tx];
  __syncthreads();
#pragma unroll
  for (int j = 0; j < 4; ++j)
    WvT[(size_t)(c0 + ty + j * 8) * D_DIM + r0 + tx] = f2bf(tile[tx][ty + j * 8]);
}

// cvec[j] = sum(dw) * dot(Wo[j,:], bv) + bo[j].  One wave per j.
__global__ void bias_kernel(const float* __restrict__ Wo, const float* __restrict__ bv,
                            const float* __restrict__ bo, const float* __restrict__ dw,
                            float* __restrict__ cvec) {
  const int j    = blockIdx.x * 4 + (threadIdx.x >> 6);
  const int lane = threadIdx.x & 63;
  float sumw = 0.f;
#pragma unroll
  for (int i = 0; i < 32; ++i) sumw += dw[i];
  float s = 0.f;
  for (int k = lane; k < D_DIM; k += 64) s += Wo[(size_t)j * D_DIM + k] * bv[k];
#pragma unroll
  for (int off = 32; off; off >>= 1) s += __shfl_xor(s, off, 64);
  if (lane == 0) cvec[j] = sumw * s + bo[j];
}

// ---------------------------------------------------------------------------
extern "C" void kernel_launch(void* const* d_in, const int* in_sizes, int n_in,
                              void* d_out, int out_size, void* d_ws, size_t ws_size,
                              hipStream_t stream) {
  const float* x  = (const float*)d_in[0];
  const float* Wv = (const float*)d_in[1];
  const float* bv = (const float*)d_in[2];
  const float* Wo = (const float*)d_in[3];
  const float* bo = (const float*)d_in[4];
  const float* dw = (const float*)d_in[5];
  float* out = (float*)d_out;

  // Workspace layout (73.7 MB total).
  char* ws = (char*)d_ws;
  ushort* S      = (ushort*)ws;                                  // M_PAD*1024 bf16
  ushort* WoB    = (ushort*)(ws + (size_t)M_PAD * D_DIM * 2);    // 1024^2 bf16
  ushort* WvT    = WoB + (size_t)D_DIM * D_DIM;                  // 1024^2 bf16
  ushort* Wfused = WvT + (size_t)D_DIM * D_DIM;                  // 1024^2 bf16
  float*  cvec   = (float*)(Wfused + (size_t)D_DIM * D_DIM);     // 1024 fp32

  // 1) Weight prep (all tiny).
  convert_wo_kernel<<<dim3(D_DIM * D_DIM / 1024), dim3(256), 0, stream>>>(Wo, WoB);
  transpose_wv_kernel<<<dim3(32, 32), dim3(32, 8), 0, stream>>>(Wv, WvT);
  bias_kernel<<<dim3(256), dim3(256), 0, stream>>>(Wo, bv, bo, dw, cvec);

  // 2) Wfused[j,k] = sum_p Wo[j,p] * Wv[p,k]   (= (Wo@Wv), stored row-major bf16).
  gemm_bt_kernel<1><<<dim3(8, 8), dim3(256), 0, stream>>>(
      WoB, WvT, nullptr, Wfused, nullptr, D_DIM, D_DIM, 1 << 30);

  // 3) Temporal conv -> s bf16 (+ zero GEMM padding rows).
  conv_kernel<<<dim3(33, B_DIM), dim3(256), 0, stream>>>(x, dw, S);
  zero_pad_kernel<<<dim3(M_PAD - M_REAL), dim3(256), 0, stream>>>(S);

  // 4) out = s @ Wfused^T + cvec.
  gemm_bt_kernel<0><<<dim3(8, M_PAD / 128), dim3(256), 0, stream>>>(
      S, Wfused, out, nullptr, cvec, D_DIM, D_DIM, M_REAL);
}

// Round 2
// 249.218 us; speedup vs baseline: 1.2426x; 1.2426x over previous
//
#include <hip/hip_runtime.h>
#include <stdint.h>

// Problem constants (from reference): B=8, T=4096, D=1024, H=32.
#define D_DIM 1024
#define T_DIM 4096
#define B_DIM 8
#define M_REAL (B_DIM * (T_DIM + 1))   // 32776 output rows
#define M_PAD  32896                    // 257 * 128 (GEMM tile padding)

typedef short short8 __attribute__((ext_vector_type(8)));   // 8 bf16 (4 VGPRs)
typedef float floatx4 __attribute__((ext_vector_type(4)));  // 4 fp32 acc

typedef const __attribute__((address_space(1))) void* gptr_t;
typedef __attribute__((address_space(3))) void* lptr_t;

__device__ __forceinline__ ushort f2bf(float f) {
  union { float f; uint32_t u; } v; v.f = f;
  uint32_t r = v.u + 0x7FFF + ((v.u >> 16) & 1);  // RNE
  return (ushort)(r >> 16);
}

// ---------------------------------------------------------------------------
// gemm_bt: C[m,n] = sum_k A[m,k] * B[n,k]  (+ bias[n]); A,B bf16 row-major
// (K contiguous), 128x128 tile, BK=64, 4 waves (2x2 of 64x64), 16x16x32 MFMA.
// m97 structure: global_load_lds width-16 staging, 2 barriers per K-step.
// WRITE_BF16=1 -> Cb (bf16, no bias/guard); 0 -> Cf (fp32, +bias, m<m_limit).
// SWIZZLE=1 -> XCD-bijective remap for grid (8, 257): consecutive original
// block ids (8 n-blocks sharing one A m-panel) land on the SAME XCD so the
// A-panel is served from that XCD's L2 (m204 bijective formula, r=0 case).
// ---------------------------------------------------------------------------
template<int WRITE_BF16, int SWIZZLE>
__global__ __launch_bounds__(256) void gemm_bt_kernel(
    const ushort* __restrict__ A, const ushort* __restrict__ Bm,
    float* __restrict__ Cf, ushort* __restrict__ Cb,
    const float* __restrict__ bias, int K, int N, int m_limit)
{
  __shared__ ushort As[128][64];   // 16 KB
  __shared__ ushort Bs[128][64];   // 16 KB
  const int tid  = threadIdx.x;
  const int wave = tid >> 6;
  const int lane = tid & 63;
  const int wm = wave >> 1, wn = wave & 1;

  int m0, n0;
  if (SWIZZLE) {
    // hw linear id; hw assigns XCD = bid % 8. nwg = 2056 = 8 * 257.
    const int bid  = blockIdx.y * 8 + blockIdx.x;
    const int orig = (bid & 7) * 257 + (bid >> 3);   // bijective remap
    n0 = (orig & 7) * 128;
    m0 = (orig >> 3) * 128;
  } else {
    n0 = blockIdx.x * 128;
    m0 = blockIdx.y * 128;
  }
  const int l15 = lane & 15, lhi = lane >> 4;

  floatx4 acc[4][4] = {};

  // Staging map: chunk = q*256 + tid; row = chunk>>3; k8 = (chunk&7)*8.
  // LDS dest is wave-uniform base + lane*16 (HW rule), so base = (q*256+wave*64)*16.
  const int srow = tid >> 3;
  const int sk8  = (tid & 7) * 8;
  const ushort* Ab = A  + (size_t)(m0 + srow) * K + sk8;
  const ushort* Bb = Bm + (size_t)(n0 + srow) * K + sk8;

  for (int k0 = 0; k0 < K; k0 += 64) {
#pragma unroll
    for (int q = 0; q < 4; ++q)
      __builtin_amdgcn_global_load_lds((gptr_t)(Ab + k0 + (size_t)q * 32 * K),
          (lptr_t)((char*)&As[0][0] + (q * 256 + wave * 64) * 16), 16, 0, 0);
#pragma unroll
    for (int q = 0; q < 4; ++q)
      __builtin_amdgcn_global_load_lds((gptr_t)(Bb + k0 + (size_t)q * 32 * K),
          (lptr_t)((char*)&Bs[0][0] + (q * 256 + wave * 64) * 16), 16, 0, 0);
    __syncthreads();

#pragma unroll
    for (int kk = 0; kk < 2; ++kk) {
      short8 af[4], bfr[4];
#pragma unroll
      for (int i = 0; i < 4; ++i) {
        af[i]  = *(const short8*)(&As[wm * 64 + i * 16 + l15][kk * 32 + lhi * 8]);
        bfr[i] = *(const short8*)(&Bs[wn * 64 + i * 16 + l15][kk * 32 + lhi * 8]);
      }
#pragma unroll
      for (int mi = 0; mi < 4; ++mi)
#pragma unroll
        for (int ni = 0; ni < 4; ++ni)
          acc[mi][ni] = __builtin_amdgcn_mfma_f32_16x16x32_bf16(
              af[mi], bfr[ni], acc[mi][ni], 0, 0, 0);
    }
    __syncthreads();
  }

  // Epilogue. C/D layout: col = lane&15, row = (lane>>4)*4 + j (m89-verified).
#pragma unroll
  for (int mi = 0; mi < 4; ++mi)
#pragma unroll
    for (int ni = 0; ni < 4; ++ni) {
      const int gn = n0 + wn * 64 + ni * 16 + l15;
      float bia = 0.0f;
      if (!WRITE_BF16) bia = bias[gn];
#pragma unroll
      for (int j = 0; j < 4; ++j) {
        const int gm = m0 + wm * 64 + mi * 16 + lhi * 4 + j;
        if (WRITE_BF16) {
          Cb[(size_t)gm * N + gn] = f2bf(acc[mi][ni][j]);
        } else {
          if (gm < m_limit) Cf[(size_t)gm * N + gn] = acc[mi][ni][j] + bia;
        }
      }
    }
}

// ---------------------------------------------------------------------------
// Depthwise temporal conv -> s_bf16 [M_PAD][1024].
// s[b,t,:] = sum_{i=0}^{31} w[i] * x[b, t-32+i, :]   (x[neg] = 0), t in [0,4096].
// Stable descending recurrence: s[t-1] = r*s[t] + w0*x[t-33] - (w31*r)*x[t-1].
// TCH=32 t-steps per block -> grid 129x8 = 1032 blocks (~4 blocks/CU) so TLP
// hides the dependent-load latency. x (134 MB) < L3, re-reads absorbed.
// ---------------------------------------------------------------------------
#define TCH 32
__global__ __launch_bounds__(256) void conv_kernel(
    const float* __restrict__ x, const float* __restrict__ dw,
    ushort* __restrict__ S)
{
  const int b  = blockIdx.y;
  const int d4 = threadIdx.x;               // 0..255 (float4 columns)
  const int t0 = blockIdx.x * TCH;
  const int t_hi = min(t0 + TCH - 1, T_DIM);   // T_DIM = last valid t (4096)

  float w[32];
#pragma unroll
  for (int i = 0; i < 32; ++i) w[i] = dw[i];
  const float r    = w[1] / w[0];
  const float w0   = w[0];
  const float cr32 = w[31] * r;             // C * r^32

  const float4* xb = (const float4*)(x + (size_t)b * T_DIM * D_DIM) + d4;

  float sx = 0.f, sy = 0.f, sz = 0.f, swv = 0.f;
#pragma unroll
  for (int i = 0; i < 32; ++i) {
    const int idx = t_hi - 32 + i;
    if (idx >= 0) {
      float4 v = xb[(size_t)idx * 256];
      sx += w[i] * v.x; sy += w[i] * v.y; sz += w[i] * v.z; swv += w[i] * v.w;
    }
  }
  {
    ushort4 o = make_ushort4(f2bf(sx), f2bf(sy), f2bf(sz), f2bf(swv));
    *(ushort4*)(S + (size_t)(b * (T_DIM + 1) + t_hi) * D_DIM + d4 * 4) = o;
  }
  for (int t = t_hi; t > t0; --t) {
    float ax = 0.f, ay = 0.f, az = 0.f, aw = 0.f;
    const int ia = t - 33;
    if (ia >= 0) {
      float4 v = xb[(size_t)ia * 256];
      ax = v.x; ay = v.y; az = v.z; aw = v.w;
    }
    const float4 vc = xb[(size_t)(t - 1) * 256];
    sx  = r * sx  + w0 * ax - cr32 * vc.x;
    sy  = r * sy  + w0 * ay - cr32 * vc.y;
    sz  = r * sz  + w0 * az - cr32 * vc.z;
    swv = r * swv + w0 * aw - cr32 * vc.w;
    ushort4 o = make_ushort4(f2bf(sx), f2bf(sy), f2bf(sz), f2bf(swv));
    *(ushort4*)(S + (size_t)(b * (T_DIM + 1) + (t - 1)) * D_DIM + d4 * 4) = o;
  }
}

// Zero the GEMM padding rows of S (rows M_REAL..M_PAD-1).
__global__ void zero_pad_kernel(ushort* __restrict__ S) {
  const int row = M_REAL + blockIdx.x;
  *(ushort4*)(S + (size_t)row * D_DIM + threadIdx.x * 4) = make_ushort4(0, 0, 0, 0);
}

// Wo fp32 -> bf16 straight copy.
__global__ void convert_wo_kernel(const float* __restrict__ Wo, ushort* __restrict__ WoB) {
  const int i = blockIdx.x * 256 + threadIdx.x;      // float4 index
  const float4 v = ((const float4*)Wo)[i];
  ushort4 o = make_ushort4(f2bf(v.x), f2bf(v.y), f2bf(v.z), f2bf(v.w));
  *(ushort4*)(WoB + (size_t)i * 4) = o;
}

// Wv fp32 -> WvT bf16 (transpose via LDS 32x32 tile).
__global__ void transpose_wv_kernel(const float* __restrict__ Wv, ushort* __restrict__ WvT) {
  __shared__ float tile[32][33];
  const int tx = threadIdx.x;   // 0..31
  const int ty = threadIdx.y;   // 0..7
  const int c0 = blockIdx.x * 32;
  const int r0 = blockIdx.y * 32;
#pragma unroll
  for (int j = 0; j < 4; ++j)
    tile[ty + j * 8][tx] = Wv[(size_t)(r0 + ty + j * 8) * D_DIM + c0 + tx];
  __syncthreads();
#pragma unroll
  for (int j = 0; j < 4; ++j)
    WvT[(size_t)(c0 + ty + j * 8) * D_DIM + r0 + tx] = f2bf(tile[tx][ty + j * 8]);
}

// cvec[j] = sum(dw) * dot(Wo[j,:], bv) + bo[j].  One wave per j.
__global__ void bias_kernel(const float* __restrict__ Wo, const float* __restrict__ bv,
                            const float* __restrict__ bo, const float* __restrict__ dw,
                            float* __restrict__ cvec) {
  const int j    = blockIdx.x * 4 + (threadIdx.x >> 6);
  const int lane = threadIdx.x & 63;
  float sumw = 0.f;
#pragma unroll
  for (int i = 0; i < 32; ++i) sumw += dw[i];
  float s = 0.f;
  for (int k = lane; k < D_DIM; k += 64) s += Wo[(size_t)j * D_DIM + k] * bv[k];
#pragma unroll
  for (int off = 32; off; off >>= 1) s += __shfl_xor(s, off, 64);
  if (lane == 0) cvec[j] = sumw * s + bo[j];
}

// ---------------------------------------------------------------------------
extern "C" void kernel_launch(void* const* d_in, const int* in_sizes, int n_in,
                              void* d_out, int out_size, void* d_ws, size_t ws_size,
                              hipStream_t stream) {
  const float* x  = (const float*)d_in[0];
  const float* Wv = (const float*)d_in[1];
  const float* bv = (const float*)d_in[2];
  const float* Wo = (const float*)d_in[3];
  const float* bo = (const float*)d_in[4];
  const float* dw = (const float*)d_in[5];
  float* out = (float*)d_out;

  // Workspace layout (73.7 MB total).
  char* ws = (char*)d_ws;
  ushort* S      = (ushort*)ws;                                  // M_PAD*1024 bf16
  ushort* WoB    = (ushort*)(ws + (size_t)M_PAD * D_DIM * 2);    // 1024^2 bf16
  ushort* WvT    = WoB + (size_t)D_DIM * D_DIM;                  // 1024^2 bf16
  ushort* Wfused = WvT + (size_t)D_DIM * D_DIM;                  // 1024^2 bf16
  float*  cvec   = (float*)(Wfused + (size_t)D_DIM * D_DIM);     // 1024 fp32

  // 1) Weight prep (all tiny).
  convert_wo_kernel<<<dim3(D_DIM * D_DIM / 1024), dim3(256), 0, stream>>>(Wo, WoB);
  transpose_wv_kernel<<<dim3(32, 32), dim3(32, 8), 0, stream>>>(Wv, WvT);
  bias_kernel<<<dim3(256), dim3(256), 0, stream>>>(Wo, bv, bo, dw, cvec);

  // 2) Wfused[j,k] = sum_p Wo[j,p] * Wv[p,k]   (= (Wo@Wv), stored row-major bf16).
  gemm_bt_kernel<1, 0><<<dim3(8, 8), dim3(256), 0, stream>>>(
      WoB, WvT, nullptr, Wfused, nullptr, D_DIM, D_DIM, 1 << 30);

  // 3) Temporal conv -> s bf16 (+ zero GEMM padding rows).
  conv_kernel<<<dim3((T_DIM / TCH) + 1, B_DIM), dim3(256), 0, stream>>>(x, dw, S);
  zero_pad_kernel<<<dim3(M_PAD - M_REAL), dim3(256), 0, stream>>>(S);

  // 4) out = s @ Wfused^T + cvec  (XCD-swizzled).
  gemm_bt_kernel<0, 1><<<dim3(8, M_PAD / 128), dim3(256), 0, stream>>>(
      S, Wfused, out, nullptr, cvec, D_DIM, D_DIM, M_REAL);
}